// Round 7
// baseline (1664.561 us; speedup 1.0000x reference)
//
#include <hip/hip_runtime.h>
#include <cstdint>
#include <cstddef>

#define NPTS 8192
#define NBATCH 4
#define KNN 10
#define NPAIR 45
#define TILE 512
#define EPSD 1e-6

// Serial per-thread, FULL DOUBLE PRECISION for all decision-relevant math
// (validator reference is numpy float64; binary output => decisions must match).
// knn: top-10 by d2 ascending (== w descending; ties -> lower index), no exp needed.
// Grid = NBATCH*NPTS/256 = 128 blocks of 256 threads. Stages f32 mean in d_out.
__global__ __launch_bounds__(256) void gfm_serial(const float* __restrict__ src,
                                                  const float* __restrict__ tgt,
                                                  float* __restrict__ mean_out) {
  __shared__ double sx[TILE], sy[TILE], sz[TILE], ssq[TILE];
  __shared__ int snbr[256][KNN];

  const int tid = threadIdx.x;
  const int b = blockIdx.x >> 5;                  // 32 blocks per batch
  const int n = ((blockIdx.x & 31) << 8) + tid;   // 0..8191

  const float* __restrict__ sb = src + (size_t)b * 3 * NPTS;
  const float* __restrict__ tb = tgt + (size_t)b * 3 * NPTS;

  const double xn = (double)sb[n], yn = (double)sb[NPTS + n], zn = (double)sb[2 * NPTS + n];
  const double sqn = xn * xn + yn * yn + zn * zn;

  // ---- Phase 1: top-10 smallest d2 (ties -> lower index), f64 ----
  double bd2[KNN];
  int bidx[KNN];
#pragma unroll
  for (int q = 0; q < KNN; ++q) { bd2[q] = 1e300; bidx[q] = 0x7FFFFFFF; }

  for (int t0 = 0; t0 < NPTS; t0 += TILE) {
    __syncthreads();
#pragma unroll
    for (int r = 0; r < TILE / 256; ++r) {
      int i = tid + r * 256;
      double x = (double)sb[t0 + i];
      double y = (double)sb[NPTS + t0 + i];
      double z = (double)sb[2 * NPTS + t0 + i];
      sx[i] = x; sy[i] = y; sz[i] = z;
      ssq[i] = x * x + y * y + z * z;
    }
    __syncthreads();
    for (int j = 0; j < TILE; ++j) {
      int m = t0 + j;
      double dot = xn * sx[j] + yn * sy[j] + zn * sz[j];
      double d2 = sqn + ssq[j] - 2.0 * dot;
      if (d2 < 0.0) d2 = 0.0;
      if (d2 < bd2[KNN - 1]) {
        // static select-network insertion, ascending d2, strict < (equal keeps
        // existing earlier-index entry first == top_k tie semantics)
        double nd[KNN]; int ni[KNN];
        bool in0 = d2 < bd2[0];
        nd[0] = in0 ? d2 : bd2[0];
        ni[0] = in0 ? m : bidx[0];
#pragma unroll
        for (int q = 1; q < KNN; ++q) {
          bool sh = d2 < bd2[q - 1];   // old q-1 shifts into q
          bool in_ = d2 < bd2[q];      // else new goes here
          nd[q] = sh ? bd2[q - 1] : (in_ ? d2 : bd2[q]);
          ni[q] = sh ? bidx[q - 1] : (in_ ? m : bidx[q]);
        }
#pragma unroll
        for (int q = 0; q < KNN; ++q) { bd2[q] = nd[q]; bidx[q] = ni[q]; }
      }
    }
  }

#pragma unroll
  for (int q = 0; q < KNN; ++q) snbr[tid][q] = bidx[q];

  // ---- Phase 2: 45 pairs, f64, serial per thread ----
  const double txn = (double)tb[n], tyn = (double)tb[NPTS + n], tzn = (double)tb[2 * NPTS + n];
  double regA[NPAIR], srt[NPAIR], tot[NPAIR], tmp[NPAIR];

  for (int p = 0; p < NPAIR; ++p) {
    // combinations(range(10),2)
    int a = 0, rem = p, len = 9;
    while (rem >= len) { rem -= len; --len; ++a; }
    int bb = a + 1 + rem;
    int g1 = snbr[tid][a];
    int g2 = snbr[tid][bb];

    double ax = (double)sb[g1] - xn, ay = (double)sb[NPTS + g1] - yn, az = (double)sb[2 * NPTS + g1] - zn;
    double bx = (double)sb[g2] - xn, by = (double)sb[NPTS + g2] - yn, bz = (double)sb[2 * NPTS + g2] - zn;
    double cx = ay * bz - az * by;
    double cy = az * bx - ax * bz;
    double cz = ax * by - ay * bx;
    double s  = cx * cx + cy * cy + cz * cz;
    double a_s = (s > 0.0) ? 0.5 * sqrt(s) : 0.0;

    double ux = (double)tb[g1] - txn, uy = (double)tb[NPTS + g1] - tyn, uz = (double)tb[2 * NPTS + g1] - tzn;
    double vx = (double)tb[g2] - txn, vy = (double)tb[NPTS + g2] - tyn, vz = (double)tb[2 * NPTS + g2] - tzn;
    double wx = uy * vz - uz * vy;
    double wy = uz * vx - ux * vz;
    double wz = ux * vy - uy * vx;
    double t2 = wx * wx + wy * wy + wz * wz;
    double a_t = (t2 > 0.0) ? 0.5 * sqrt(t2) : 0.0;

    // src_l = [0,0,a_s]; tgt_l = [eps,eps,a_t+eps]
    double ate = a_t + EPSD;
    double d   = a_s - ate;
    double numer = (EPSD * EPSD + EPSD * EPSD) + d * d;
    double denom = (EPSD + EPSD) + (a_s + ate);
    srt[p]  = numer / denom;     // loss (pre-sort)
    regA[p] = sqrt(numer);
  }

  for (int i = 1; i < NPAIR; ++i) {            // insertion sort ascending
    double x = srt[i]; int j = i - 1;
    while (j >= 0 && srt[j] > x) { srt[j + 1] = srt[j]; --j; }
    srt[j + 1] = x;
  }
  for (int p = 0; p < NPAIR; ++p) { tot[p] = srt[p] + 0.1 * regA[p]; tmp[p] = tot[p]; }
  for (int i = 1; i < NPAIR; ++i) {
    double x = tmp[i]; int j = i - 1;
    while (j >= 0 && tmp[j] > x) { tmp[j + 1] = tmp[j]; --j; }
    tmp[j + 1] = x;
  }
  double med = tmp[(NPAIR - 1) / 2];           // lower median = sorted[22]

  double sum = 0.0;
  for (int p = 0; p < KNN; ++p) {
    double t = tot[p];
    t = (t > 3.0 * med) ? 0.0 : t;
    sum += sqrt(t + EPSD);
  }
  mean_out[b * NPTS + n] = (float)(sum / 10.0);
}

// One block per batch: min-reduce f32 means (from d_out), decide via f64
// sigmoid, overwrite d_out in place with binary f32.
__global__ __launch_bounds__(1024) void gfm_finalize(float* __restrict__ buf) {
  __shared__ float red[16];
  const int b = blockIdx.x;
  const int tid = threadIdx.x;
  float* __restrict__ mb = buf + b * NPTS;

  float v[8];
  float mn = 3.4e38f;
#pragma unroll
  for (int r = 0; r < 8; ++r) {
    v[r] = mb[tid + r * 1024];
    mn = fminf(mn, v[r]);
  }
#pragma unroll
  for (int s = 32; s >= 1; s >>= 1)
    mn = fminf(mn, __shfl_xor(mn, s, 64));
  if ((tid & 63) == 0) red[tid >> 6] = mn;
  __syncthreads();
  mn = red[0];
#pragma unroll
  for (int q = 1; q < 16; ++q) mn = fminf(mn, red[q]);
  __syncthreads();   // all reads of mb done before any write below

#pragma unroll
  for (int r = 0; r < 8; ++r) {
    double t = (double)v[r] - (double)mn;
    double w = 2.0 / (1.0 + exp(20.0 * t));
    mb[tid + r * 1024] = (w > 0.5) ? 1.0f : 0.0f;
  }
}

extern "C" void kernel_launch(void* const* d_in, const int* in_sizes, int n_in,
                              void* d_out, int out_size, void* d_ws, size_t ws_size,
                              hipStream_t stream) {
  const float* src = (const float*)d_in[0];
  const float* tgt = (const float*)d_in[1];
  float* out = (float*)d_out;   // f32 [4,8192]; staged with mean_loss, finalized in place

  gfm_serial<<<NBATCH * NPTS / 256, 256, 0, stream>>>(src, tgt, out);
  gfm_finalize<<<NBATCH, 1024, 0, stream>>>(out);
}

// Round 8
// 992.468 us; speedup vs baseline: 1.6772x; 1.6772x over previous
//
#include <hip/hip_runtime.h>
#include <cstdint>
#include <cstddef>

#define NPTS 8192
#define NBATCH 4
#define KNN 10
#define NPAIR 45
#define TILE 512
#define EPSD 1e-6

// Wave-per-point, f64 decision math (validated in round 7).
// Block = 256 thr = 4 waves = 4 points (same batch). Grid = 4*8192/4 = 8192.
__global__ __launch_bounds__(256) void gfm_wave(const float* __restrict__ src,
                                                const float* __restrict__ tgt,
                                                float* __restrict__ mean_out) {
  __shared__ float  sx[TILE], sy[TILE], sz[TILE];
  __shared__ double ssq[TILE];
  __shared__ double lsA[4][NPAIR];
  __shared__ double lsB[4][NPAIR];
  __shared__ double smed[4];
  __shared__ double ssum[4][KNN];
  __shared__ int    snbr[4][KNN];

  const int tid  = threadIdx.x;
  const int wv   = tid >> 6;
  const int lane = tid & 63;
  const int b    = blockIdx.x >> 11;                // 2048 blocks per batch
  const int n    = ((blockIdx.x & 2047) << 2) | wv; // point id

  const float* __restrict__ sb = src + (size_t)b * 3 * NPTS;
  const float* __restrict__ tb = tgt + (size_t)b * 3 * NPTS;

  const double xn = (double)sb[n], yn = (double)sb[NPTS + n], zn = (double)sb[2 * NPTS + n];
  const double sqn = xn * xn + yn * yn + zn * zn;

  // ---- Phase 1: per-lane top-10 of (d2 asc, idx asc), lanes cover j = lane+64k ----
  double bd2[KNN];
  int    bidx[KNN];
#pragma unroll
  for (int q = 0; q < KNN; ++q) { bd2[q] = 1e300; bidx[q] = 0x7FFFFFFF; }

  for (int t0 = 0; t0 < NPTS; t0 += TILE) {
    __syncthreads();
#pragma unroll
    for (int r = 0; r < TILE / 256; ++r) {
      int i = tid + r * 256;
      float x = sb[t0 + i], y = sb[NPTS + t0 + i], z = sb[2 * NPTS + t0 + i];
      sx[i] = x; sy[i] = y; sz[i] = z;
      double dx = (double)x, dy = (double)y, dz = (double)z;
      ssq[i] = dx * dx + dy * dy + dz * dz;
    }
    __syncthreads();
#pragma unroll 2
    for (int j = lane; j < TILE; j += 64) {
      int m = t0 + j;
      double dot = xn * (double)sx[j] + yn * (double)sy[j] + zn * (double)sz[j];
      double d2 = sqn + ssq[j] - 2.0 * dot;
      if (d2 < 0.0) d2 = 0.0;
      // lexicographic (d2, idx) — idx unique so no full tie possible
      if (d2 < bd2[KNN - 1]) {
        double nd[KNN]; int ni[KNN];
        bool in0 = (d2 < bd2[0]);
        nd[0] = in0 ? d2 : bd2[0];
        ni[0] = in0 ? m : bidx[0];
#pragma unroll
        for (int q = 1; q < KNN; ++q) {
          bool sh  = (d2 < bd2[q - 1]);
          bool in_ = (d2 < bd2[q]);
          nd[q] = sh ? bd2[q - 1] : (in_ ? d2 : bd2[q]);
          ni[q] = sh ? bidx[q - 1] : (in_ ? m : bidx[q]);
        }
#pragma unroll
        for (int q = 0; q < KNN; ++q) { bd2[q] = nd[q]; bidx[q] = ni[q]; }
      }
    }
  }

  // ---- Wave merge: 10 rounds of lexicographic argmin over lane heads ----
#pragma unroll
  for (int r = 0; r < KNN; ++r) {
    double d = bd2[0];
    int    i = bidx[0];
#pragma unroll
    for (int s = 32; s >= 1; s >>= 1) {
      double od = __shfl_xor(d, s, 64);
      int    oi = __shfl_xor(i, s, 64);
      if (od < d || (od == d && oi < i)) { d = od; i = oi; }
    }
    if (lane == 0) snbr[wv][r] = i;
    if (bd2[0] == d && bidx[0] == i) {   // unique owner pops
#pragma unroll
      for (int q = 0; q < KNN - 1; ++q) { bd2[q] = bd2[q + 1]; bidx[q] = bidx[q + 1]; }
      bd2[KNN - 1] = 1e300; bidx[KNN - 1] = 0x7FFFFFFF;
    }
  }
  __syncthreads();

  // ---- Phase 2: 45 pairs, one lane each, all f64 ----
  const double txn = (double)tb[n], tyn = (double)tb[NPTS + n], tzn = (double)tb[2 * NPTS + n];
  const int p = lane;
  double loss = 0.0, reg = 0.0;
  if (p < NPAIR) {
    int a = 0, rem = p, len = 9;
    while (rem >= len) { rem -= len; --len; ++a; }
    int bb = a + 1 + rem;
    int g1 = snbr[wv][a];
    int g2 = snbr[wv][bb];

    double ax = (double)sb[g1] - xn, ay = (double)sb[NPTS + g1] - yn, az = (double)sb[2 * NPTS + g1] - zn;
    double bx = (double)sb[g2] - xn, by = (double)sb[NPTS + g2] - yn, bz = (double)sb[2 * NPTS + g2] - zn;
    double cx = ay * bz - az * by;
    double cy = az * bx - ax * bz;
    double cz = ax * by - ay * bx;
    double s  = cx * cx + cy * cy + cz * cz;
    double a_s = (s > 0.0) ? 0.5 * sqrt(s) : 0.0;

    double ux = (double)tb[g1] - txn, uy = (double)tb[NPTS + g1] - tyn, uz = (double)tb[2 * NPTS + g1] - tzn;
    double vx = (double)tb[g2] - txn, vy = (double)tb[NPTS + g2] - tyn, vz = (double)tb[2 * NPTS + g2] - tzn;
    double wx = uy * vz - uz * vy;
    double wy = uz * vx - ux * vz;
    double wz = ux * vy - uy * vx;
    double t2 = wx * wx + wy * wy + wz * wz;
    double a_t = (t2 > 0.0) ? 0.5 * sqrt(t2) : 0.0;

    double ate = a_t + EPSD;
    double d   = a_s - ate;
    double numer = (EPSD * EPSD + EPSD * EPSD) + d * d;
    double denom = (EPSD + EPSD) + (a_s + ate);
    loss = numer / denom;
    reg  = sqrt(numer);
    lsA[wv][p] = loss;
  }
  __syncthreads();

  // rank-sort losses (unique ranks via index tie-break; sorted VALUES == np.sort)
  if (p < NPAIR) {
    int rk = 0;
    for (int m = 0; m < NPAIR; ++m) {
      double lm = lsA[wv][m];
      rk += (lm < loss) || (lm == loss && m < p);
    }
    lsB[wv][rk] = loss;
  }
  __syncthreads();
  double tot = 0.0;
  if (p < NPAIR) {
    tot = lsB[wv][p] + 0.1 * reg;
    lsA[wv][p] = tot;
  }
  __syncthreads();
  if (p < NPAIR) {
    int rk = 0;
    for (int m = 0; m < NPAIR; ++m) {
      double tm = lsA[wv][m];
      rk += (tm < tot) || (tm == tot && m < p);
    }
    if (rk == (NPAIR - 1) / 2) smed[wv] = tot;   // lower median = sorted[22]
  }
  __syncthreads();
  double med = smed[wv];
  if (p < KNN) {
    double t = (tot > 3.0 * med) ? 0.0 : tot;
    ssum[wv][p] = sqrt(t + EPSD);
  }
  __syncthreads();
  if (lane == 0) {
    double sum = 0.0;
#pragma unroll
    for (int q = 0; q < KNN; ++q) sum += ssum[wv][q];
    mean_out[b * NPTS + n] = (float)(sum / 10.0);
  }
}

// One block per batch: min-reduce f32 means (staged in d_out), decide via f64
// sigmoid, overwrite d_out in place with binary f32. (Identical to round 7.)
__global__ __launch_bounds__(1024) void gfm_finalize(float* __restrict__ buf) {
  __shared__ float red[16];
  const int b = blockIdx.x;
  const int tid = threadIdx.x;
  float* __restrict__ mb = buf + b * NPTS;

  float v[8];
  float mn = 3.4e38f;
#pragma unroll
  for (int r = 0; r < 8; ++r) {
    v[r] = mb[tid + r * 1024];
    mn = fminf(mn, v[r]);
  }
#pragma unroll
  for (int s = 32; s >= 1; s >>= 1)
    mn = fminf(mn, __shfl_xor(mn, s, 64));
  if ((tid & 63) == 0) red[tid >> 6] = mn;
  __syncthreads();
  mn = red[0];
#pragma unroll
  for (int q = 1; q < 16; ++q) mn = fminf(mn, red[q]);
  __syncthreads();   // all reads of mb done before any write below

#pragma unroll
  for (int r = 0; r < 8; ++r) {
    double t = (double)v[r] - (double)mn;
    double w = 2.0 / (1.0 + exp(20.0 * t));
    mb[tid + r * 1024] = (w > 0.5) ? 1.0f : 0.0f;
  }
}

extern "C" void kernel_launch(void* const* d_in, const int* in_sizes, int n_in,
                              void* d_out, int out_size, void* d_ws, size_t ws_size,
                              hipStream_t stream) {
  const float* src = (const float*)d_in[0];
  const float* tgt = (const float*)d_in[1];
  float* out = (float*)d_out;   // f32 [4,8192]; staged with mean_loss, finalized in place

  gfm_wave<<<NBATCH * NPTS / 4, 256, 0, stream>>>(src, tgt, out);
  gfm_finalize<<<NBATCH, 1024, 0, stream>>>(out);
}

// Round 9
// 628.195 us; speedup vs baseline: 2.6498x; 1.5799x over previous
//
#include <hip/hip_runtime.h>
#include <cstdint>
#include <cstddef>

#define NPTS 8192
#define NBATCH 4
#define KNN 10
#define NPAIR 45
#define TILE 512
#define MARGIN 12
#define EPSD 1e-6

// Wave-per-point. Phase 1: f32 packed-key top-12 scan + exact f64 re-rank.
// Phase 2: f64 (proven in rounds 7/8).
// Block = 256 thr = 4 waves = 4 points (same batch). Grid = 4*8192/4 = 8192.
__global__ __launch_bounds__(256) void gfm_wave(const float* __restrict__ src,
                                                const float* __restrict__ tgt,
                                                float* __restrict__ mean_out) {
  __shared__ float4 s4[TILE];
  __shared__ double lsA[4][NPAIR];
  __shared__ double lsB[4][NPAIR];
  __shared__ double smed[4];
  __shared__ double ssum[4][KNN];
  __shared__ double rd2[4][MARGIN];
  __shared__ int    rid[4][MARGIN];
  __shared__ int    snbr[4][KNN];

  const int tid  = threadIdx.x;
  const int wv   = tid >> 6;
  const int lane = tid & 63;
  const int b    = blockIdx.x >> 11;                // 2048 blocks per batch
  const int n    = ((blockIdx.x & 2047) << 2) | wv; // point id

  const float* __restrict__ sb = src + (size_t)b * 3 * NPTS;
  const float* __restrict__ tb = tgt + (size_t)b * 3 * NPTS;

  const float xnf = sb[n], ynf = sb[NPTS + n], znf = sb[2 * NPTS + n];
  const float sqnf = xnf * xnf + ynf * ynf + znf * znf;

  // ---- Phase 1 scan: per-lane top-12 packed (f32 d2 bits, idx) keys ----
  uint64_t loc[MARGIN];
#pragma unroll
  for (int q = 0; q < MARGIN; ++q) loc[q] = ~0ull;

  for (int t0 = 0; t0 < NPTS; t0 += TILE) {
    __syncthreads();
#pragma unroll
    for (int r = 0; r < TILE / 256; ++r) {
      int i = tid + r * 256;
      float x = sb[t0 + i], y = sb[NPTS + t0 + i], z = sb[2 * NPTS + t0 + i];
      s4[i] = make_float4(x, y, z, x * x + y * y + z * z);
    }
    __syncthreads();
#pragma unroll 2
    for (int r = 0; r < TILE / 64; ++r) {
      int j = lane + (r << 6);
      float4 c = s4[j];
      float dot = xnf * c.x + ynf * c.y + znf * c.z;
      float d2 = fmaxf(sqnf + c.w - 2.0f * dot, 0.0f);
      uint64_t key = ((uint64_t)__float_as_uint(d2) << 32) | (uint32_t)(t0 + j);
      if (key < loc[MARGIN - 1]) {
        uint64_t nl[MARGIN];
        nl[0] = (key < loc[0]) ? key : loc[0];
#pragma unroll
        for (int q = 1; q < MARGIN; ++q) {
          bool sh  = key < loc[q - 1];   // old q-1 shifts into q
          bool in_ = key < loc[q];
          nl[q] = sh ? loc[q - 1] : (in_ ? key : loc[q]);
        }
#pragma unroll
        for (int q = 0; q < MARGIN; ++q) loc[q] = nl[q];
      }
    }
  }

  // ---- Wave merge: 12 rounds of u64 argmin over lane heads ----
#pragma unroll
  for (int r = 0; r < MARGIN; ++r) {
    uint64_t mk = loc[0];
#pragma unroll
    for (int s = 32; s >= 1; s >>= 1) {
      uint64_t ok = (uint64_t)__shfl_xor((unsigned long long)mk, s, 64);
      mk = (ok < mk) ? ok : mk;
    }
    if (lane == 0) rid[wv][r] = (int)(uint32_t)(mk & 0xFFFFFFFFull);
    if (loc[0] == mk) {   // unique owner (idx embedded) pops its head
#pragma unroll
      for (int q = 0; q < MARGIN - 1; ++q) loc[q] = loc[q + 1];
      loc[MARGIN - 1] = ~0ull;
    }
  }
  __syncthreads();

  // ---- Exact f64 re-rank of the 12 candidates (reference op order) ----
  const double xn = (double)xnf, yn = (double)ynf, zn = (double)znf;
  const double sqn = xn * xn + yn * yn + zn * zn;
  double myd2 = 0.0;
  int myid = 0;
  if (lane < MARGIN) {
    myid = rid[wv][lane];
    double gx = (double)sb[myid], gy = (double)sb[NPTS + myid], gz = (double)sb[2 * NPTS + myid];
    double gsq = gx * gx + gy * gy + gz * gz;
    double dot = xn * gx + yn * gy + zn * gz;
    double d2 = sqn + gsq - 2.0 * dot;
    if (d2 < 0.0) d2 = 0.0;
    myd2 = d2;
    rd2[wv][lane] = d2;
  }
  __syncthreads();
  if (lane < MARGIN) {
    int rk = 0;
    for (int m = 0; m < MARGIN; ++m) {
      double dm = rd2[wv][m];
      rk += (dm < myd2) || (dm == myd2 && rid[wv][m] < myid);
    }
    if (rk < KNN) snbr[wv][rk] = myid;
  }
  __syncthreads();

  // ---- Phase 2: 45 pairs, one lane each, all f64 (identical to round 8) ----
  const double txn = (double)tb[n], tyn = (double)tb[NPTS + n], tzn = (double)tb[2 * NPTS + n];
  const int p = lane;
  double loss = 0.0, reg = 0.0;
  if (p < NPAIR) {
    int a = 0, rem = p, len = 9;
    while (rem >= len) { rem -= len; --len; ++a; }
    int bb = a + 1 + rem;
    int g1 = snbr[wv][a];
    int g2 = snbr[wv][bb];

    double ax = (double)sb[g1] - xn, ay = (double)sb[NPTS + g1] - yn, az = (double)sb[2 * NPTS + g1] - zn;
    double bx = (double)sb[g2] - xn, by = (double)sb[NPTS + g2] - yn, bz = (double)sb[2 * NPTS + g2] - zn;
    double cx = ay * bz - az * by;
    double cy = az * bx - ax * bz;
    double cz = ax * by - ay * bx;
    double s  = cx * cx + cy * cy + cz * cz;
    double a_s = (s > 0.0) ? 0.5 * sqrt(s) : 0.0;

    double ux = (double)tb[g1] - txn, uy = (double)tb[NPTS + g1] - tyn, uz = (double)tb[2 * NPTS + g1] - tzn;
    double vx = (double)tb[g2] - txn, vy = (double)tb[NPTS + g2] - tyn, vz = (double)tb[2 * NPTS + g2] - tzn;
    double wx = uy * vz - uz * vy;
    double wy = uz * vx - ux * vz;
    double wz = ux * vy - uy * vx;
    double t2 = wx * wx + wy * wy + wz * wz;
    double a_t = (t2 > 0.0) ? 0.5 * sqrt(t2) : 0.0;

    double ate = a_t + EPSD;
    double d   = a_s - ate;
    double numer = (EPSD * EPSD + EPSD * EPSD) + d * d;
    double denom = (EPSD + EPSD) + (a_s + ate);
    loss = numer / denom;
    reg  = sqrt(numer);
    lsA[wv][p] = loss;
  }
  __syncthreads();

  if (p < NPAIR) {
    int rk = 0;
    for (int m = 0; m < NPAIR; ++m) {
      double lm = lsA[wv][m];
      rk += (lm < loss) || (lm == loss && m < p);
    }
    lsB[wv][rk] = loss;
  }
  __syncthreads();
  double tot = 0.0;
  if (p < NPAIR) {
    tot = lsB[wv][p] + 0.1 * reg;
    lsA[wv][p] = tot;
  }
  __syncthreads();
  if (p < NPAIR) {
    int rk = 0;
    for (int m = 0; m < NPAIR; ++m) {
      double tm = lsA[wv][m];
      rk += (tm < tot) || (tm == tot && m < p);
    }
    if (rk == (NPAIR - 1) / 2) smed[wv] = tot;   // lower median = sorted[22]
  }
  __syncthreads();
  double med = smed[wv];
  if (p < KNN) {
    double t = (tot > 3.0 * med) ? 0.0 : tot;
    ssum[wv][p] = sqrt(t + EPSD);
  }
  __syncthreads();
  if (lane == 0) {
    double sum = 0.0;
#pragma unroll
    for (int q = 0; q < KNN; ++q) sum += ssum[wv][q];
    mean_out[b * NPTS + n] = (float)(sum / 10.0);
  }
}

// One block per batch: min-reduce f32 means (staged in d_out), decide via f64
// sigmoid, overwrite d_out in place with binary f32. (Identical to round 8.)
__global__ __launch_bounds__(1024) void gfm_finalize(float* __restrict__ buf) {
  __shared__ float red[16];
  const int b = blockIdx.x;
  const int tid = threadIdx.x;
  float* __restrict__ mb = buf + b * NPTS;

  float v[8];
  float mn = 3.4e38f;
#pragma unroll
  for (int r = 0; r < 8; ++r) {
    v[r] = mb[tid + r * 1024];
    mn = fminf(mn, v[r]);
  }
#pragma unroll
  for (int s = 32; s >= 1; s >>= 1)
    mn = fminf(mn, __shfl_xor(mn, s, 64));
  if ((tid & 63) == 0) red[tid >> 6] = mn;
  __syncthreads();
  mn = red[0];
#pragma unroll
  for (int q = 1; q < 16; ++q) mn = fminf(mn, red[q]);
  __syncthreads();   // all reads of mb done before any write below

#pragma unroll
  for (int r = 0; r < 8; ++r) {
    double t = (double)v[r] - (double)mn;
    double w = 2.0 / (1.0 + exp(20.0 * t));
    mb[tid + r * 1024] = (w > 0.5) ? 1.0f : 0.0f;
  }
}

extern "C" void kernel_launch(void* const* d_in, const int* in_sizes, int n_in,
                              void* d_out, int out_size, void* d_ws, size_t ws_size,
                              hipStream_t stream) {
  const float* src = (const float*)d_in[0];
  const float* tgt = (const float*)d_in[1];
  float* out = (float*)d_out;   // f32 [4,8192]; staged with mean_loss, finalized in place

  gfm_wave<<<NBATCH * NPTS / 4, 256, 0, stream>>>(src, tgt, out);
  gfm_finalize<<<NBATCH, 1024, 0, stream>>>(out);
}

// Round 10
// 239.293 us; speedup vs baseline: 6.9562x; 2.6252x over previous
//
#include <hip/hip_runtime.h>
#include <cstdint>
#include <cstddef>

#define NPTS 8192
#define NBATCH 4
#define KNN 10
#define NPAIR 45
#define TILE 512
#define MARGIN 12
#define QSZ 96        // max queue 79 + 12 top copy
#define DRAIN_AT 16
#define EPSD 1e-6

// Wave-per-point. Phase 1: f32 packed-key scan with wave-uniform tau filter +
// ballot-compacted LDS queue (exact top-12), then f64 re-rank. Phase 2: f64.
// Block = 256 thr = 4 waves = 4 points (same batch). Grid = 8192.
__global__ __launch_bounds__(256) void gfm_wave(const float* __restrict__ src,
                                                const float* __restrict__ tgt,
                                                float* __restrict__ mean_out) {
  __shared__ float4   s4[TILE];
  __shared__ uint64_t sq[4][QSZ];
  __shared__ uint64_t stp[4][MARGIN];
  __shared__ double lsA[4][NPAIR];
  __shared__ double lsB[4][NPAIR];
  __shared__ double smed[4];
  __shared__ double ssum[4][KNN];
  __shared__ double rd2[4][MARGIN];
  __shared__ int    rid[4][MARGIN];
  __shared__ int    snbr[4][KNN];

  const int tid  = threadIdx.x;
  const int wv   = tid >> 6;
  const int lane = tid & 63;
  const int b    = blockIdx.x >> 11;                // 2048 blocks per batch
  const int n    = ((blockIdx.x & 2047) << 2) | wv; // point id

  const float* __restrict__ sb = src + (size_t)b * 3 * NPTS;
  const float* __restrict__ tb = tgt + (size_t)b * 3 * NPTS;

  const float xnf = sb[n], ynf = sb[NPTS + n], znf = sb[2 * NPTS + n];
  const float sqnf = xnf * xnf + ynf * ynf + znf * znf;

  // ---- Phase 1: tau-filtered scan, exact wave top-12 of (f32 d2 bits, idx) ----
  if (lane < MARGIN) stp[wv][lane] = ~0ull;
  __builtin_amdgcn_wave_barrier();
  uint64_t tau = ~0ull;   // wave-uniform
  int qn = 0;             // wave-uniform

  auto drain = [&]() {
    // merge queue[0..qn) + top12 -> new sorted top12, tighten tau
    if (lane < MARGIN) sq[wv][qn + lane] = stp[wv][lane];
    __builtin_amdgcn_wave_barrier();
    const int tot = qn + MARGIN;   // <= 91, keys unique (idx embedded; init
                                   // pads all rank >= tot-12 >= 12, never kept)
    uint64_t k0 = (lane < tot) ? sq[wv][lane] : ~0ull;
    uint64_t k1 = (lane + 64 < tot) ? sq[wv][lane + 64] : ~0ull;
    int r0 = 0, r1 = 0;
    for (int m = 0; m < tot; ++m) {
      uint64_t km = sq[wv][m];
      r0 += (km < k0);
      r1 += (km < k1);
    }
    __builtin_amdgcn_wave_barrier();
    if (lane < tot && r0 < MARGIN) stp[wv][r0] = k0;
    if (lane + 64 < tot && r1 < MARGIN) stp[wv][r1] = k1;
    __builtin_amdgcn_wave_barrier();
    tau = stp[wv][MARGIN - 1];
    qn = 0;
  };

  for (int t0 = 0; t0 < NPTS; t0 += TILE) {
    __syncthreads();
#pragma unroll
    for (int r = 0; r < TILE / 256; ++r) {
      int i = tid + r * 256;
      float x = sb[t0 + i], y = sb[NPTS + t0 + i], z = sb[2 * NPTS + t0 + i];
      s4[i] = make_float4(x, y, z, x * x + y * y + z * z);
    }
    __syncthreads();
#pragma unroll 2
    for (int r = 0; r < TILE / 64; ++r) {
      int j = lane + (r << 6);
      float4 c = s4[j];
      float dot = fmaf(xnf, c.x, fmaf(ynf, c.y, znf * c.z));
      float d2 = fmaxf(fmaf(-2.0f, dot, sqnf + c.w), 0.0f);
      uint64_t key = ((uint64_t)__float_as_uint(d2) << 32) | (uint32_t)(t0 + j);
      bool pred = key < tau;
      uint64_t mask = __ballot(pred);
      if (mask) {                     // wave-uniform branch
        int below = __builtin_amdgcn_mbcnt_hi((uint32_t)(mask >> 32),
                     __builtin_amdgcn_mbcnt_lo((uint32_t)mask, 0));
        if (pred) sq[wv][qn + below] = key;
        __builtin_amdgcn_wave_barrier();
        qn += __popcll(mask);
        if (qn >= DRAIN_AT) drain();
      }
    }
  }
  if (qn > 0) drain();

  if (lane < MARGIN) rid[wv][lane] = (int)(uint32_t)(stp[wv][lane] & 0xFFFFFFFFull);
  __syncthreads();

  // ---- Exact f64 re-rank of the 12 candidates (reference op order) ----
  const double xn = (double)xnf, yn = (double)ynf, zn = (double)znf;
  const double sqn = xn * xn + yn * yn + zn * zn;
  double myd2 = 0.0;
  int myid = 0;
  if (lane < MARGIN) {
    myid = rid[wv][lane];
    double gx = (double)sb[myid], gy = (double)sb[NPTS + myid], gz = (double)sb[2 * NPTS + myid];
    double gsq = gx * gx + gy * gy + gz * gz;
    double dot = xn * gx + yn * gy + zn * gz;
    double d2 = sqn + gsq - 2.0 * dot;
    if (d2 < 0.0) d2 = 0.0;
    myd2 = d2;
    rd2[wv][lane] = d2;
  }
  __syncthreads();
  if (lane < MARGIN) {
    int rk = 0;
    for (int m = 0; m < MARGIN; ++m) {
      double dm = rd2[wv][m];
      rk += (dm < myd2) || (dm == myd2 && rid[wv][m] < myid);
    }
    if (rk < KNN) snbr[wv][rk] = myid;
  }
  __syncthreads();

  // ---- Phase 2: 45 pairs, one lane each, all f64 (identical to round 8/9) ----
  const double txn = (double)tb[n], tyn = (double)tb[NPTS + n], tzn = (double)tb[2 * NPTS + n];
  const int p = lane;
  double loss = 0.0, reg = 0.0;
  if (p < NPAIR) {
    int a = 0, rem = p, len = 9;
    while (rem >= len) { rem -= len; --len; ++a; }
    int bb = a + 1 + rem;
    int g1 = snbr[wv][a];
    int g2 = snbr[wv][bb];

    double ax = (double)sb[g1] - xn, ay = (double)sb[NPTS + g1] - yn, az = (double)sb[2 * NPTS + g1] - zn;
    double bx = (double)sb[g2] - xn, by = (double)sb[NPTS + g2] - yn, bz = (double)sb[2 * NPTS + g2] - zn;
    double cx = ay * bz - az * by;
    double cy = az * bx - ax * bz;
    double cz = ax * by - ay * bx;
    double s  = cx * cx + cy * cy + cz * cz;
    double a_s = (s > 0.0) ? 0.5 * sqrt(s) : 0.0;

    double ux = (double)tb[g1] - txn, uy = (double)tb[NPTS + g1] - tyn, uz = (double)tb[2 * NPTS + g1] - tzn;
    double vx = (double)tb[g2] - txn, vy = (double)tb[NPTS + g2] - tyn, vz = (double)tb[2 * NPTS + g2] - tzn;
    double wx = uy * vz - uz * vy;
    double wy = uz * vx - ux * vz;
    double wz = ux * vy - uy * vx;
    double t2 = wx * wx + wy * wy + wz * wz;
    double a_t = (t2 > 0.0) ? 0.5 * sqrt(t2) : 0.0;

    double ate = a_t + EPSD;
    double d   = a_s - ate;
    double numer = (EPSD * EPSD + EPSD * EPSD) + d * d;
    double denom = (EPSD + EPSD) + (a_s + ate);
    loss = numer / denom;
    reg  = sqrt(numer);
    lsA[wv][p] = loss;
  }
  __syncthreads();

  if (p < NPAIR) {
    int rk = 0;
    for (int m = 0; m < NPAIR; ++m) {
      double lm = lsA[wv][m];
      rk += (lm < loss) || (lm == loss && m < p);
    }
    lsB[wv][rk] = loss;
  }
  __syncthreads();
  double tot2 = 0.0;
  if (p < NPAIR) {
    tot2 = lsB[wv][p] + 0.1 * reg;
    lsA[wv][p] = tot2;
  }
  __syncthreads();
  if (p < NPAIR) {
    int rk = 0;
    for (int m = 0; m < NPAIR; ++m) {
      double tm = lsA[wv][m];
      rk += (tm < tot2) || (tm == tot2 && m < p);
    }
    if (rk == (NPAIR - 1) / 2) smed[wv] = tot2;   // lower median = sorted[22]
  }
  __syncthreads();
  double med = smed[wv];
  if (p < KNN) {
    double t = (tot2 > 3.0 * med) ? 0.0 : tot2;
    ssum[wv][p] = sqrt(t + EPSD);
  }
  __syncthreads();
  if (lane == 0) {
    double sum = 0.0;
#pragma unroll
    for (int q = 0; q < KNN; ++q) sum += ssum[wv][q];
    mean_out[b * NPTS + n] = (float)(sum / 10.0);
  }
}

// One block per batch: min-reduce f32 means (staged in d_out), decide via f64
// sigmoid, overwrite d_out in place with binary f32. (Identical to round 8/9.)
__global__ __launch_bounds__(1024) void gfm_finalize(float* __restrict__ buf) {
  __shared__ float red[16];
  const int b = blockIdx.x;
  const int tid = threadIdx.x;
  float* __restrict__ mb = buf + b * NPTS;

  float v[8];
  float mn = 3.4e38f;
#pragma unroll
  for (int r = 0; r < 8; ++r) {
    v[r] = mb[tid + r * 1024];
    mn = fminf(mn, v[r]);
  }
#pragma unroll
  for (int s = 32; s >= 1; s >>= 1)
    mn = fminf(mn, __shfl_xor(mn, s, 64));
  if ((tid & 63) == 0) red[tid >> 6] = mn;
  __syncthreads();
  mn = red[0];
#pragma unroll
  for (int q = 1; q < 16; ++q) mn = fminf(mn, red[q]);
  __syncthreads();   // all reads of mb done before any write below

#pragma unroll
  for (int r = 0; r < 8; ++r) {
    double t = (double)v[r] - (double)mn;
    double w = 2.0 / (1.0 + exp(20.0 * t));
    mb[tid + r * 1024] = (w > 0.5) ? 1.0f : 0.0f;
  }
}

extern "C" void kernel_launch(void* const* d_in, const int* in_sizes, int n_in,
                              void* d_out, int out_size, void* d_ws, size_t ws_size,
                              hipStream_t stream) {
  const float* src = (const float*)d_in[0];
  const float* tgt = (const float*)d_in[1];
  float* out = (float*)d_out;   // f32 [4,8192]; staged with mean_loss, finalized in place

  gfm_wave<<<NBATCH * NPTS / 4, 256, 0, stream>>>(src, tgt, out);
  gfm_finalize<<<NBATCH, 1024, 0, stream>>>(out);
}

// Round 11
// 233.928 us; speedup vs baseline: 7.1157x; 1.0229x over previous
//
#include <hip/hip_runtime.h>
#include <cstdint>
#include <cstddef>

#define NPTS 8192
#define NBATCH 4
#define KNN 10
#define NPAIR 45
#define TILE 512
#define MARGIN 12
#define QSZ 96        // >= max qn (79) + MARGIN
#define DRAIN_AT 16
#define EPSD 1e-6

__device__ __constant__ int dCOMB_A[NPAIR] = {
  0,0,0,0,0,0,0,0,0, 1,1,1,1,1,1,1,1, 2,2,2,2,2,2,2,
  3,3,3,3,3,3, 4,4,4,4,4, 5,5,5,5, 6,6,6, 7,7, 8};
__device__ __constant__ int dCOMB_B[NPAIR] = {
  1,2,3,4,5,6,7,8,9, 2,3,4,5,6,7,8,9, 3,4,5,6,7,8,9,
  4,5,6,7,8,9, 5,6,7,8,9, 6,7,8,9, 7,8,9, 8,9, 9};

// Pack src points to float4 (x,y,z,|p|^2) in d_ws.
__global__ __launch_bounds__(256) void pack_pts(const float* __restrict__ src,
                                                float4* __restrict__ pk) {
  int i = blockIdx.x * 256 + threadIdx.x;        // 0..32767
  int b = i >> 13, p = i & (NPTS - 1);
  const float* sb = src + (size_t)b * 3 * NPTS;
  float x = sb[p], y = sb[NPTS + p], z = sb[2 * NPTS + p];
  pk[i] = make_float4(x, y, z, x * x + y * y + z * z);
}

// Wave-per-point. Phase 1: f32 tau-prefiltered scan, ballot-compacted queue,
// exact top-12, f64 re-rank. Phase 2: f64 (proven rounds 7-10).
// Block = 256 thr = 4 waves = 4 points (same batch). Grid = 8192.
template <bool PACKED>
__global__ __launch_bounds__(256) void gfm_wave(const float* __restrict__ src,
                                                const float* __restrict__ tgt,
                                                const float4* __restrict__ pk,
                                                float* __restrict__ mean_out) {
  __shared__ float4   s4[TILE];
  __shared__ uint64_t sq[4][QSZ];
  __shared__ uint64_t stp[4][MARGIN];
  __shared__ double lsA[4][NPAIR];
  __shared__ double lsB[4][NPAIR];
  __shared__ double smed[4];
  __shared__ double ssum[4][KNN];
  __shared__ double rd2[4][MARGIN];
  __shared__ int    rid[4][MARGIN];
  __shared__ int    snbr[4][KNN];

  const int tid  = threadIdx.x;
  const int wv   = tid >> 6;
  const int lane = tid & 63;
  const int b    = blockIdx.x >> 11;                // 2048 blocks per batch
  const int n    = ((blockIdx.x & 2047) << 2) | wv; // point id

  const float* __restrict__ sb = src + (size_t)b * 3 * NPTS;
  const float* __restrict__ tb = tgt + (size_t)b * 3 * NPTS;

  const float xnf = sb[n], ynf = sb[NPTS + n], znf = sb[2 * NPTS + n];
  const float sqnf = xnf * xnf + ynf * ynf + znf * znf;

  // ---- Phase 1: f32-prefiltered scan, exact wave top-12 of (d2 bits, idx) ----
  if (lane < MARGIN) stp[wv][lane] = ~0ull;
  __builtin_amdgcn_wave_barrier();
  float tau_f = __builtin_inff();   // f32 d2 of 12th-best (wave-uniform)
  int qn = 0;                       // wave-uniform

  auto drain = [&]() {
    if (lane < MARGIN) sq[wv][qn + lane] = stp[wv][lane];
    __builtin_amdgcn_wave_barrier();
    const int tot = qn + MARGIN;    // <= 91; keys unique (idx embedded)
    uint64_t k0 = (lane < tot) ? sq[wv][lane] : ~0ull;
    uint64_t k1 = (lane + 64 < tot) ? sq[wv][lane + 64] : ~0ull;
    int r0 = 0, r1 = 0;
    for (int m = 0; m < tot; ++m) {
      uint64_t km = sq[wv][m];
      r0 += (km < k0);
      r1 += (km < k1);
    }
    __builtin_amdgcn_wave_barrier();
    if (lane < tot && r0 < MARGIN) stp[wv][r0] = k0;
    if (lane + 64 < tot && r1 < MARGIN) stp[wv][r1] = k1;
    __builtin_amdgcn_wave_barrier();
    tau_f = __uint_as_float((uint32_t)(stp[wv][MARGIN - 1] >> 32));
    qn = 0;
  };

  for (int t0 = 0; t0 < NPTS; t0 += TILE) {
    __syncthreads();
    if (PACKED) {
      const float4* __restrict__ g = pk + (size_t)b * NPTS + t0;
#pragma unroll
      for (int r = 0; r < TILE / 256; ++r) {
        int i = tid + r * 256;
        s4[i] = g[i];
      }
    } else {
#pragma unroll
      for (int r = 0; r < TILE / 256; ++r) {
        int i = tid + r * 256;
        float x = sb[t0 + i], y = sb[NPTS + t0 + i], z = sb[2 * NPTS + t0 + i];
        s4[i] = make_float4(x, y, z, x * x + y * y + z * z);
      }
    }
    __syncthreads();
#pragma unroll 2
    for (int r = 0; r < TILE / 64; ++r) {
      int j = lane + (r << 6);
      float4 c = s4[j];
      float dot = fmaf(xnf, c.x, fmaf(ynf, c.y, znf * c.z));
      float d2 = fmaxf(fmaf(-2.0f, dot, sqnf + c.w), 0.0f);
      bool pred = d2 <= tau_f;           // superset of exact key<tau
      uint64_t mask = __ballot(pred);
      if (mask) {                        // wave-uniform branch
        uint64_t key = ((uint64_t)__float_as_uint(d2) << 32) | (uint32_t)(t0 + j);
        int below = __builtin_amdgcn_mbcnt_hi((uint32_t)(mask >> 32),
                     __builtin_amdgcn_mbcnt_lo((uint32_t)mask, 0));
        if (pred) sq[wv][qn + below] = key;
        __builtin_amdgcn_wave_barrier();
        qn += __popcll(mask);
        if (qn >= DRAIN_AT) drain();
      }
    }
  }
  if (qn > 0) drain();

  if (lane < MARGIN) rid[wv][lane] = (int)(uint32_t)(stp[wv][lane] & 0xFFFFFFFFull);
  __syncthreads();

  // ---- Exact f64 re-rank of the 12 candidates (reference op order) ----
  const double xn = (double)xnf, yn = (double)ynf, zn = (double)znf;
  const double sqn = xn * xn + yn * yn + zn * zn;
  double myd2 = 0.0;
  int myid = 0;
  if (lane < MARGIN) {
    myid = rid[wv][lane];
    double gx = (double)sb[myid], gy = (double)sb[NPTS + myid], gz = (double)sb[2 * NPTS + myid];
    double gsq = gx * gx + gy * gy + gz * gz;
    double dot = xn * gx + yn * gy + zn * gz;
    double d2 = sqn + gsq - 2.0 * dot;
    if (d2 < 0.0) d2 = 0.0;
    myd2 = d2;
    rd2[wv][lane] = d2;
  }
  __syncthreads();
  if (lane < MARGIN) {
    int rk = 0;
    for (int m = 0; m < MARGIN; ++m) {
      double dm = rd2[wv][m];
      rk += (dm < myd2) || (dm == myd2 && rid[wv][m] < myid);
    }
    if (rk < KNN) snbr[wv][rk] = myid;
  }
  __syncthreads();

  // ---- Phase 2: 45 pairs, one lane each, all f64 (identical to rounds 8-10) ----
  const double txn = (double)tb[n], tyn = (double)tb[NPTS + n], tzn = (double)tb[2 * NPTS + n];
  const int p = lane;
  double loss = 0.0, reg = 0.0;
  if (p < NPAIR) {
    int g1 = snbr[wv][dCOMB_A[p]];
    int g2 = snbr[wv][dCOMB_B[p]];

    double ax = (double)sb[g1] - xn, ay = (double)sb[NPTS + g1] - yn, az = (double)sb[2 * NPTS + g1] - zn;
    double bx = (double)sb[g2] - xn, by = (double)sb[NPTS + g2] - yn, bz = (double)sb[2 * NPTS + g2] - zn;
    double cx = ay * bz - az * by;
    double cy = az * bx - ax * bz;
    double cz = ax * by - ay * bx;
    double s  = cx * cx + cy * cy + cz * cz;
    double a_s = (s > 0.0) ? 0.5 * sqrt(s) : 0.0;

    double ux = (double)tb[g1] - txn, uy = (double)tb[NPTS + g1] - tyn, uz = (double)tb[2 * NPTS + g1] - tzn;
    double vx = (double)tb[g2] - txn, vy = (double)tb[NPTS + g2] - tyn, vz = (double)tb[2 * NPTS + g2] - tzn;
    double wx = uy * vz - uz * vy;
    double wy = uz * vx - ux * vz;
    double wz = ux * vy - uy * vx;
    double t2 = wx * wx + wy * wy + wz * wz;
    double a_t = (t2 > 0.0) ? 0.5 * sqrt(t2) : 0.0;

    double ate = a_t + EPSD;
    double d   = a_s - ate;
    double numer = (EPSD * EPSD + EPSD * EPSD) + d * d;
    double denom = (EPSD + EPSD) + (a_s + ate);
    loss = numer / denom;
    reg  = sqrt(numer);
    lsA[wv][p] = loss;
  }
  __syncthreads();

  if (p < NPAIR) {
    int rk = 0;
    for (int m = 0; m < NPAIR; ++m) {
      double lm = lsA[wv][m];
      rk += (lm < loss) || (lm == loss && m < p);
    }
    lsB[wv][rk] = loss;
  }
  __syncthreads();
  double tot2 = 0.0;
  if (p < NPAIR) {
    tot2 = lsB[wv][p] + 0.1 * reg;
    lsA[wv][p] = tot2;
  }
  __syncthreads();
  if (p < NPAIR) {
    int rk = 0;
    for (int m = 0; m < NPAIR; ++m) {
      double tm = lsA[wv][m];
      rk += (tm < tot2) || (tm == tot2 && m < p);
    }
    if (rk == (NPAIR - 1) / 2) smed[wv] = tot2;   // lower median = sorted[22]
  }
  __syncthreads();
  double med = smed[wv];
  if (p < KNN) {
    double t = (tot2 > 3.0 * med) ? 0.0 : tot2;
    ssum[wv][p] = sqrt(t + EPSD);
  }
  __syncthreads();
  if (lane == 0) {
    double sum = 0.0;
#pragma unroll
    for (int q = 0; q < KNN; ++q) sum += ssum[wv][q];
    mean_out[b * NPTS + n] = (float)(sum / 10.0);
  }
}

// One block per batch: min-reduce f32 means (staged in d_out), decide via f64
// sigmoid, overwrite d_out in place with binary f32. (Identical to rounds 8-10.)
__global__ __launch_bounds__(1024) void gfm_finalize(float* __restrict__ buf) {
  __shared__ float red[16];
  const int b = blockIdx.x;
  const int tid = threadIdx.x;
  float* __restrict__ mb = buf + b * NPTS;

  float v[8];
  float mn = 3.4e38f;
#pragma unroll
  for (int r = 0; r < 8; ++r) {
    v[r] = mb[tid + r * 1024];
    mn = fminf(mn, v[r]);
  }
#pragma unroll
  for (int s = 32; s >= 1; s >>= 1)
    mn = fminf(mn, __shfl_xor(mn, s, 64));
  if ((tid & 63) == 0) red[tid >> 6] = mn;
  __syncthreads();
  mn = red[0];
#pragma unroll
  for (int q = 1; q < 16; ++q) mn = fminf(mn, red[q]);
  __syncthreads();   // all reads of mb done before any write below

#pragma unroll
  for (int r = 0; r < 8; ++r) {
    double t = (double)v[r] - (double)mn;
    double w = 2.0 / (1.0 + exp(20.0 * t));
    mb[tid + r * 1024] = (w > 0.5) ? 1.0f : 0.0f;
  }
}

extern "C" void kernel_launch(void* const* d_in, const int* in_sizes, int n_in,
                              void* d_out, int out_size, void* d_ws, size_t ws_size,
                              hipStream_t stream) {
  const float* src = (const float*)d_in[0];
  const float* tgt = (const float*)d_in[1];
  float* out = (float*)d_out;   // f32 [4,8192]; staged with mean_loss, finalized in place
  float4* pk = (float4*)d_ws;   // packed (x,y,z,|p|^2), 512 KiB

  if (ws_size >= (size_t)NBATCH * NPTS * sizeof(float4)) {
    pack_pts<<<NBATCH * NPTS / 256, 256, 0, stream>>>(src, pk);
    gfm_wave<true><<<NBATCH * NPTS / 4, 256, 0, stream>>>(src, tgt, pk, out);
  } else {
    gfm_wave<false><<<NBATCH * NPTS / 4, 256, 0, stream>>>(src, tgt, pk, out);
  }
  gfm_finalize<<<NBATCH, 1024, 0, stream>>>(out);
}